// Round 10
// baseline (206.628 us; speedup 1.0000x reference)
//
#include <hip/hip_runtime.h>
#include <hip/hip_bf16.h>

#define BATCH 4
#define SEQ   2048
#define DIM   1024
#define NHEAD 16
#define HDIM  64

typedef __bf16    bf16x8 __attribute__((ext_vector_type(8)));
typedef float     f32x16 __attribute__((ext_vector_type(16)));
typedef unsigned  u32;

__device__ __forceinline__ unsigned short f2bfu(float x) {
  union { __hip_bfloat16 b; unsigned short u; } c; c.b = __float2bfloat16(x); return c.u;
}
__device__ __forceinline__ u32 cvtpk(float lo, float hi) {
  u32 r; asm("v_cvt_pk_bf16_f32 %0, %1, %2" : "=v"(r) : "v"(lo), "v"(hi)); return r;
}
__device__ __forceinline__ int swz4(int row) {
  return ((row & 7) ^ ((row >> 3) & 7)) << 2;
}

// async 16B global->LDS (linear LDS dest: wave-uniform base + lane*16)
#define GLDS16(GP, LP)                                                         \
  __builtin_amdgcn_global_load_lds(                                            \
      (const __attribute__((address_space(1))) void*)(GP),                     \
      (__attribute__((address_space(3))) void*)(LP), 16, 0, 0)

// ---------------------------------------------------------------------------
// Weight transpose+convert: Wt[n][k] = bf16(W[k][n]). 64x64 tile per block.
// ---------------------------------------------------------------------------
__global__ __launch_bounds__(256)
void wtrans(const float* __restrict__ w0, const float* __restrict__ w1,
            const float* __restrict__ w2,
            __hip_bfloat16* __restrict__ t0, __hip_bfloat16* __restrict__ t1,
            __hip_bfloat16* __restrict__ t2)
{
  __shared__ float T[64][68];
  const int mat  = blockIdx.x >> 8;
  const int tile = blockIdx.x & 255;
  const float* W = mat == 0 ? w0 : (mat == 1 ? w1 : w2);
  __hip_bfloat16* Wt = mat == 0 ? t0 : (mat == 1 ? t1 : t2);
  const int k0 = (tile >> 4) * 64, n0 = (tile & 15) * 64;
  const int tid = threadIdx.x;
  const int r = tid >> 2, cq = (tid & 3) * 16;
  #pragma unroll
  for (int j = 0; j < 4; ++j) {
    const float4 v = *reinterpret_cast<const float4*>(&W[(size_t)(k0 + r) * DIM + n0 + cq + j * 4]);
    T[r][cq + j * 4 + 0] = v.x; T[r][cq + j * 4 + 1] = v.y;
    T[r][cq + j * 4 + 2] = v.z; T[r][cq + j * 4 + 3] = v.w;
  }
  __syncthreads();
  u32 o[8];
  #pragma unroll
  for (int j = 0; j < 8; ++j)
    o[j] = cvtpk(T[cq + 2 * j][r], T[cq + 2 * j + 1][r]);
  *reinterpret_cast<uint4*>(&Wt[(size_t)(n0 + r) * DIM + k0 + cq + 0]) = make_uint4(o[0], o[1], o[2], o[3]);
  *reinterpret_cast<uint4*>(&Wt[(size_t)(n0 + r) * DIM + k0 + cq + 8]) = make_uint4(o[4], o[5], o[6], o[7]);
}

// ---------------------------------------------------------------------------
// 1-phase GEMM, bf16-only 32KB LDS (single-buffered) -> 4 blocks/CU.
// fp32 A: reg-stage (loads issued before compute, cvt+ds_write after barrier).
// bf16 A: GLDS16 direct. B (bf16 Wt[N][K]): GLDS16, pre-swizzled source.
// Per-segment output scale (folds softmax scale into Q).
// 128x128 tile, BK=64, 4 waves 2x2 of 64x64, 32x32x16 MFMA.
// ---------------------------------------------------------------------------
template<typename TIN, typename TOUT, int NSEG>
__global__ __launch_bounds__(256, 2)
void gemm1ph(const TIN* __restrict__ A0, const TIN* __restrict__ A1, const TIN* __restrict__ A2,
             const __hip_bfloat16* __restrict__ W0, const __hip_bfloat16* __restrict__ W1,
             const __hip_bfloat16* __restrict__ W2,
             const float* __restrict__ b0, const float* __restrict__ b1, const float* __restrict__ b2,
             TOUT* __restrict__ C0, TOUT* __restrict__ C1, TOUT* __restrict__ C2,
             float s0, float s1, float s2)
{
  __shared__ __align__(16) u32 As32[128][32];   // bf16 [row][k-pairs], swizzled (16KB)
  __shared__ __align__(16) u32 Bs32[128][32];   // bf16 [col][k-pairs], swizzled (16KB)

  constexpr bool AF32 = (sizeof(TIN) == 4);
  constexpr int K = 1024, NT = 16;

  const int seg = (NSEG == 1) ? 0 : (blockIdx.x >> 9);
  const int idb = (NSEG == 1) ? blockIdx.x : (blockIdx.x & 511);
  const TIN* A = seg == 0 ? A0 : (seg == 1 ? A1 : A2);
  const __hip_bfloat16* Wt = seg == 0 ? W0 : (seg == 1 ? W1 : W2);
  const float* bias = seg == 0 ? b0 : (seg == 1 ? b1 : b2);
  TOUT* C = seg == 0 ? C0 : (seg == 1 ? C1 : C2);
  const float scl = seg == 0 ? s0 : (seg == 1 ? s1 : s2);

  const int xcd = idb & 7, rr = idb >> 3;
  const int bx = rr & 7, by = xcd + 8 * (rr >> 3);
  const int m0 = by * 128, n0 = bx * 128;

  const int tid = threadIdx.x, lane = tid & 63, w = tid >> 6;
  const int l31 = lane & 31, hi = lane >> 5;
  const int wm = w >> 1, wn = w & 1;

  f32x16 acc[2][2] = {};

  const __hip_bfloat16* bptr[4];
  #pragma unroll
  for (int i = 0; i < 4; ++i) {
    const int off = (w * 4 + i) * 1024 + lane * 16;
    const int r = off >> 7;
    const int s = (off >> 4) & 7;
    bptr[i] = Wt + (size_t)(n0 + r) * K + (s ^ (r & 7)) * 8;
  }
  const TIN* aptr[4];
  const int arow = tid >> 3;
  const int acb  = (tid & 7) * 8;
  #pragma unroll
  for (int i = 0; i < 4; ++i) {
    if constexpr (!AF32) {
      const int off = (w * 4 + i) * 1024 + lane * 16;
      const int r = off >> 7;
      const int s = (off >> 4) & 7;
      aptr[i] = A + (size_t)(m0 + r) * K + (s ^ (r & 7)) * 8;
    } else {
      aptr[i] = nullptr;
    }
  }

  float4 ar[4][2];

  auto loadA_f32 = [&](int t) {
    #pragma unroll
    for (int p = 0; p < 4; ++p) {
      const float* ap = (const float*)A + (size_t)(m0 + arow + p * 32) * K + t * 64 + acb;
      ar[p][0] = *reinterpret_cast<const float4*>(ap);
      ar[p][1] = *reinterpret_cast<const float4*>(ap + 4);
    }
  };
  auto writeA_f32 = [&]() {
    #pragma unroll
    for (int p = 0; p < 4; ++p) {
      const int row = arow + p * 32;
      uint4 pk;
      pk.x = cvtpk(ar[p][0].x, ar[p][0].y);
      pk.y = cvtpk(ar[p][0].z, ar[p][0].w);
      pk.z = cvtpk(ar[p][1].x, ar[p][1].y);
      pk.w = cvtpk(ar[p][1].z, ar[p][1].w);
      *reinterpret_cast<uint4*>(&As32[row][((tid & 7) * 4) ^ ((row & 7) << 2)]) = pk;
    }
  };
  auto stageA_bf = [&](int t) {
    #pragma unroll
    for (int i = 0; i < 4; ++i)
      GLDS16((const __hip_bfloat16*)aptr[i] + t * 64, (char*)As32 + (w * 4 + i) * 1024);
  };
  auto stageB = [&](int t) {
    #pragma unroll
    for (int i = 0; i < 4; ++i)
      GLDS16(bptr[i] + t * 64, (char*)Bs32 + (w * 4 + i) * 1024);
  };

  int aoff[4][2], boff[4][2];
  #pragma unroll
  for (int kk = 0; kk < 4; ++kk) {
    #pragma unroll
    for (int mi = 0; mi < 2; ++mi) {
      const int r = wm * 64 + mi * 32 + l31;
      aoff[kk][mi] = r * 128 + (((kk * 2 + hi) ^ (r & 7)) << 4);
    }
    #pragma unroll
    for (int ni = 0; ni < 2; ++ni) {
      const int c = wn * 64 + ni * 32 + l31;
      boff[kk][ni] = c * 128 + (((kk * 2 + hi) ^ (c & 7)) << 4);
    }
  }

  if constexpr (AF32) { loadA_f32(0); writeA_f32(); }
  else                { stageA_bf(0); }
  stageB(0);
  __syncthreads();

  for (int t = 0; t < NT; ++t) {
    if (t + 1 < NT) { if constexpr (AF32) loadA_f32(t + 1); }

    #pragma unroll
    for (int kk = 0; kk < 4; ++kk) {
      bf16x8 af[2], bfv[2];
      #pragma unroll
      for (int mi = 0; mi < 2; ++mi)
        af[mi] = *reinterpret_cast<const bf16x8*>((const char*)As32 + aoff[kk][mi]);
      #pragma unroll
      for (int ni = 0; ni < 2; ++ni)
        bfv[ni] = *reinterpret_cast<const bf16x8*>((const char*)Bs32 + boff[kk][ni]);
      __builtin_amdgcn_s_setprio(1);
      #pragma unroll
      for (int mi = 0; mi < 2; ++mi)
        #pragma unroll
        for (int ni = 0; ni < 2; ++ni)
          acc[mi][ni] = __builtin_amdgcn_mfma_f32_32x32x16_bf16(af[mi], bfv[ni], acc[mi][ni], 0, 0, 0);
      __builtin_amdgcn_s_setprio(0);
    }
    __syncthreads();

    if (t + 1 < NT) {
      if constexpr (AF32) writeA_f32();
      else                stageA_bf(t + 1);
      stageB(t + 1);
      __syncthreads();
    }
  }

  #pragma unroll
  for (int ni = 0; ni < 2; ++ni) {
    const int col = n0 + wn * 64 + ni * 32 + l31;
    const float bv = bias[col];
    #pragma unroll
    for (int mi = 0; mi < 2; ++mi) {
      #pragma unroll
      for (int g = 0; g < 4; ++g)
        #pragma unroll
        for (int e = 0; e < 4; ++e) {
          const int row = m0 + wm * 64 + mi * 32 + g * 8 + hi * 4 + e;
          const float val = (acc[mi][ni][g * 4 + e] + bv) * scl;
          if constexpr (sizeof(TOUT) == 2)
            C[(size_t)row * DIM + col] = __float2bfloat16(val);
          else
            C[(size_t)row * DIM + col] = val;
        }
    }
  }
}

// ---------------------------------------------------------------------------
// Flash attention: 512 threads = 8 waves, QB=256 (32 q-rows/wave), 512 blocks
// -> 16 waves/CU. Static-max softmax with Q pre-scaled by 0.125*log2(e)
// (exp2 directly on sacc). Swapped MFMAs, cvt_pk+permlane32_swap P fragments,
// swizzled double-buffered K/V LDS; staging spread over 512 threads.
// ---------------------------------------------------------------------------
__global__ __launch_bounds__(512, 4)
void flash_attn(const __hip_bfloat16* __restrict__ Qb,
                const __hip_bfloat16* __restrict__ Kb,
                const __hip_bfloat16* __restrict__ Vb,
                __hip_bfloat16* __restrict__ Ob)
{
  __shared__ __align__(16) u32 Ks32[2][64][32];
  __shared__ __align__(16) u32 Vt32[2][64][32];

  // 512 blocks = 8 xcd * 8 qb * 2 hh * 4 b ; h = xcd + 8*hh
  const int id  = blockIdx.x;
  const int xcd = id & 7;
  const int r_  = id >> 3;
  const int qb  = r_ & 7;
  const int hh  = (r_ >> 3) & 1;
  const int b   = r_ >> 4;
  const int h   = xcd + 8 * hh;

  const int tid = threadIdx.x, lane = tid & 63, w = tid >> 6;
  const int l31 = lane & 31, hi = lane >> 5;

  const size_t headoff = (size_t)h * HDIM;
  const int qrow = b * SEQ + qb * 256 + w * 32 + l31;   // this wave's q-row

  // Q fragments (B-operand: col=l31=qrow, k=depth); Q pre-scaled by C1
  bf16x8 qf[4];
  #pragma unroll
  for (int dk = 0; dk < 4; ++dk)
    qf[dk] = *reinterpret_cast<const bf16x8*>(
      &Qb[(size_t)qrow * DIM + headoff + dk * 16 + hi * 8]);

  f32x16 accO[2] = {};
  float l_run = 0.f;

  // staging mappings (512 threads)
  const int skey = tid >> 3;        // K: key row 0..63 (8 threads x 16B = 128B)
  const int sdq  = tid & 7;         // K: 16B granule
  const int vkp  = tid >> 4;        // V: key pair 0..31
  const int vdq  = tid & 15;        // V: depth quad 0..15 (16 threads x 8B = 128B)
  const size_t kbase = (size_t)b * SEQ * DIM + headoff;

  uint4 kst;
  uint2 vst0, vst1;
  auto load_t = [&](int t) {
    const int kb = t * 64;
    kst = *reinterpret_cast<const uint4*>(&Kb[kbase + (size_t)(kb + skey) * DIM + sdq * 8]);
    const __hip_bfloat16* vp_ = &Vb[kbase + (size_t)(kb + vkp * 2) * DIM + vdq * 4];
    vst0 = *reinterpret_cast<const uint2*>(vp_);
    vst1 = *reinterpret_cast<const uint2*>(vp_ + DIM);
  };
  auto store_t = [&](int bb) {
    *reinterpret_cast<uint4*>(&Ks32[bb][skey][(sdq * 4) ^ swz4(skey)]) = kst;
    const unsigned short* a  = (const unsigned short*)&vst0;
    const unsigned short* bv = (const unsigned short*)&vst1;
    #pragma unroll
    for (int j = 0; j < 4; ++j) {
      const int row = vdq * 4 + j;
      Vt32[bb][row][vkp ^ swz4(row)] = (u32)a[j] | ((u32)bv[j] << 16);
    }
  };

  load_t(0); store_t(0); __syncthreads();

  for (int t = 0; t < SEQ / 64; ++t) {
    const int bb = t & 1;
    if (t < SEQ / 64 - 1) load_t(t + 1);

    // ---- S^T = K * Q^T (8 MFMA) ----
    f32x16 sacc[2] = {};
    __builtin_amdgcn_s_setprio(1);
    #pragma unroll
    for (int kt = 0; kt < 2; ++kt) {
      const int row = kt * 32 + l31;
      const int sk = swz4(row);
      #pragma unroll
      for (int dk = 0; dk < 4; ++dk) {
        bf16x8 kf = *reinterpret_cast<const bf16x8*>(&Ks32[bb][row][(dk * 8 + hi * 4) ^ sk]);
        sacc[kt] = __builtin_amdgcn_mfma_f32_32x32x16_bf16(kf, qf[dk], sacc[kt], 0, 0, 0);
      }
    }
    __builtin_amdgcn_s_setprio(0);

    // ---- static-max softmax: p = exp2(sacc) directly (Q pre-scaled) ----
    #pragma unroll
    for (int kt = 0; kt < 2; ++kt)
      #pragma unroll
      for (int r2 = 0; r2 < 16; ++r2)
        sacc[kt][r2] = __builtin_amdgcn_exp2f(sacc[kt][r2]);

    f32x16 ps = sacc[0] + sacc[1];
    float s8[8];
    #pragma unroll
    for (int i = 0; i < 8; ++i) s8[i] = ps[i] + ps[i + 8];
    float rs = ((s8[0] + s8[1]) + (s8[2] + s8[3])) + ((s8[4] + s8[5]) + (s8[6] + s8[7]));
    rs += __shfl_xor(rs, 32);
    l_run += rs;

    // ---- P fragments ----
    u32 pf[4][4];
#define MAKE_PF(DST, P, B) do {                                            \
      u32 x1 = cvtpk(P[B+0], P[B+1]);                                      \
      u32 y1 = cvtpk(P[B+4], P[B+5]);                                      \
      u32 x2 = cvtpk(P[B+2], P[B+3]);                                      \
      u32 y2 = cvtpk(P[B+6], P[B+7]);                                      \
      auto s1_ = __builtin_amdgcn_permlane32_swap(x1, y1, false, false);   \
      auto s2_ = __builtin_amdgcn_permlane32_swap(x2, y2, false, false);   \
      DST[0] = (u32)s1_[0]; DST[1] = (u32)s2_[0];                          \
      DST[2] = (u32)s1_[1]; DST[3] = (u32)s2_[1];                          \
    } while (0)
    MAKE_PF(pf[0], sacc[0], 0);
    MAKE_PF(pf[1], sacc[0], 8);
    MAKE_PF(pf[2], sacc[1], 0);
    MAKE_PF(pf[3], sacc[1], 8);
#undef MAKE_PF

    // ---- O^T += V^T * P^T (8 MFMA) ----
    __builtin_amdgcn_s_setprio(1);
    #pragma unroll
    for (int dt = 0; dt < 2; ++dt) {
      const int row = dt * 32 + l31;
      const int sk = swz4(row);
      #pragma unroll
      for (int kf = 0; kf < 4; ++kf) {
        bf16x8 vf = *reinterpret_cast<const bf16x8*>(&Vt32[bb][row][(kf * 8 + hi * 4) ^ sk]);
        union { u32 u[4]; bf16x8 v; } pu;
        pu.u[0] = pf[kf][0]; pu.u[1] = pf[kf][1];
        pu.u[2] = pf[kf][2]; pu.u[3] = pf[kf][3];
        accO[dt] = __builtin_amdgcn_mfma_f32_32x32x16_bf16(vf, pu.v, accO[dt], 0, 0, 0);
      }
    }
    __builtin_amdgcn_s_setprio(0);

    if (t < SEQ / 64 - 1) store_t(bb ^ 1);
    __syncthreads();
  }

  // ---- write O ----
  const float inv = 1.f / l_run;
  const size_t rowbase = (size_t)qrow * DIM + headoff;
  #pragma unroll
  for (int dt = 0; dt < 2; ++dt)
    #pragma unroll
    for (int g = 0; g < 4; ++g) {
      ushort4 o;
      o.x = f2bfu(accO[dt][g * 4 + 0] * inv);
      o.y = f2bfu(accO[dt][g * 4 + 1] * inv);
      o.z = f2bfu(accO[dt][g * 4 + 2] * inv);
      o.w = f2bfu(accO[dt][g * 4 + 3] * inv);
      *reinterpret_cast<ushort4*>(&Ob[rowbase + dt * 32 + g * 8 + hi * 4]) = o;
    }
}

// ---------------------------------------------------------------------------
extern "C" void kernel_launch(void* const* d_in, const int* in_sizes, int n_in,
                              void* d_out, int out_size, void* d_ws, size_t ws_size,
                              hipStream_t stream)
{
  const float* q  = (const float*)d_in[0];
  const float* k  = (const float*)d_in[1];
  const float* v  = (const float*)d_in[2];
  const float* wq = (const float*)d_in[3];
  const float* bq = (const float*)d_in[4];
  const float* wk = (const float*)d_in[5];
  const float* bk = (const float*)d_in[6];
  const float* wv = (const float*)d_in[7];
  const float* bv = (const float*)d_in[8];
  const float* wo = (const float*)d_in[9];
  const float* bo = (const float*)d_in[10];

  const size_t MN = (size_t)BATCH * SEQ * DIM;   // 8388608
  const size_t KK = (size_t)DIM * DIM;           // 1048576
  const float  C1 = 0.125f * 1.44269504f;        // softmax scale * log2(e)

  __hip_bfloat16* Qb = (__hip_bfloat16*)d_ws;
  __hip_bfloat16* Kb = Qb + MN;
  __hip_bfloat16* Vb = Kb + MN;
  __hip_bfloat16* S3 = Vb + MN;     // 4th 16MB slot
  __hip_bfloat16* WtQ = S3;         // weights live here until attention
  __hip_bfloat16* WtK = S3 + KK;
  __hip_bfloat16* WtV = S3 + 2 * KK;
  __hip_bfloat16* Ob  = S3;         // attention output overwrites Wt (dead)
  __hip_bfloat16* WtO = (__hip_bfloat16*)d_ws;  // into Qb slot after attention

  wtrans<<<768, 256, 0, stream>>>(wq, wk, wv, WtQ, WtK, WtV);

  gemm1ph<float, __hip_bfloat16, 3><<<1536, 256, 0, stream>>>(
      q, k, v, WtQ, WtK, WtV, bq, bk, bv, Qb, Kb, Vb, C1, 1.0f, 1.0f);

  flash_attn<<<512, 512, 0, stream>>>(Qb, Kb, Vb, Ob);

  wtrans<<<256, 256, 0, stream>>>(wo, wo, wo, WtO, WtO, WtO);

  gemm1ph<__hip_bfloat16, float, 1><<<512, 256, 0, stream>>>(
      Ob, Ob, Ob, WtO, WtO, WtO, bo, bo, bo,
      (float*)d_out, (float*)d_out, (float*)d_out, 1.0f, 1.0f, 1.0f);
}

// Round 11
// 195.355 us; speedup vs baseline: 1.0577x; 1.0577x over previous
//
#include <hip/hip_runtime.h>
#include <hip/hip_bf16.h>

#define BATCH 4
#define SEQ   2048
#define DIM   1024
#define NHEAD 16
#define HDIM  64

typedef __bf16    bf16x8 __attribute__((ext_vector_type(8)));
typedef float     f32x16 __attribute__((ext_vector_type(16)));
typedef unsigned  u32;

__device__ __forceinline__ unsigned short f2bfu(float x) {
  union { __hip_bfloat16 b; unsigned short u; } c; c.b = __float2bfloat16(x); return c.u;
}
__device__ __forceinline__ u32 cvtpk(float lo, float hi) {
  u32 r; asm("v_cvt_pk_bf16_f32 %0, %1, %2" : "=v"(r) : "v"(lo), "v"(hi)); return r;
}
__device__ __forceinline__ int swz4(int row) {
  return ((row & 7) ^ ((row >> 3) & 7)) << 2;
}

// async 16B global->LDS (linear LDS dest: wave-uniform base + lane*16)
#define GLDS16(GP, LP)                                                         \
  __builtin_amdgcn_global_load_lds(                                            \
      (const __attribute__((address_space(1))) void*)(GP),                     \
      (__attribute__((address_space(3))) void*)(LP), 16, 0, 0)

// ---------------------------------------------------------------------------
// Weight transpose+convert: Wt[n][k] = bf16(W[k][n]). 64x64 tile per block.
// ---------------------------------------------------------------------------
__global__ __launch_bounds__(256)
void wtrans(const float* __restrict__ w0, const float* __restrict__ w1,
            const float* __restrict__ w2,
            __hip_bfloat16* __restrict__ t0, __hip_bfloat16* __restrict__ t1,
            __hip_bfloat16* __restrict__ t2)
{
  __shared__ float T[64][68];
  const int mat  = blockIdx.x >> 8;
  const int tile = blockIdx.x & 255;
  const float* W = mat == 0 ? w0 : (mat == 1 ? w1 : w2);
  __hip_bfloat16* Wt = mat == 0 ? t0 : (mat == 1 ? t1 : t2);
  const int k0 = (tile >> 4) * 64, n0 = (tile & 15) * 64;
  const int tid = threadIdx.x;
  const int r = tid >> 2, cq = (tid & 3) * 16;
  #pragma unroll
  for (int j = 0; j < 4; ++j) {
    const float4 v = *reinterpret_cast<const float4*>(&W[(size_t)(k0 + r) * DIM + n0 + cq + j * 4]);
    T[r][cq + j * 4 + 0] = v.x; T[r][cq + j * 4 + 1] = v.y;
    T[r][cq + j * 4 + 2] = v.z; T[r][cq + j * 4 + 3] = v.w;
  }
  __syncthreads();
  u32 o[8];
  #pragma unroll
  for (int j = 0; j < 8; ++j)
    o[j] = cvtpk(T[cq + 2 * j][r], T[cq + 2 * j + 1][r]);
  *reinterpret_cast<uint4*>(&Wt[(size_t)(n0 + r) * DIM + k0 + cq + 0]) = make_uint4(o[0], o[1], o[2], o[3]);
  *reinterpret_cast<uint4*>(&Wt[(size_t)(n0 + r) * DIM + k0 + cq + 8]) = make_uint4(o[4], o[5], o[6], o[7]);
}

// ---------------------------------------------------------------------------
// 1-phase GEMM, bf16 LDS. DBUFB: B double-buffered, stage(t+1) issued BEFORE
// compute(t) so B latency hides under MFMA (A stays single-buffered,
// reg-staged for fp32 with early global loads). No setprio (m190: hurts
// lockstep GEMM). 128x128 tile, BK=64, 4 waves 2x2, 32x32x16 MFMA.
// ---------------------------------------------------------------------------
template<typename TIN, typename TOUT, int NSEG, bool DBUFB>
__global__ __launch_bounds__(256, 2)
void gemm1ph(const TIN* __restrict__ A0, const TIN* __restrict__ A1, const TIN* __restrict__ A2,
             const __hip_bfloat16* __restrict__ W0, const __hip_bfloat16* __restrict__ W1,
             const __hip_bfloat16* __restrict__ W2,
             const float* __restrict__ b0, const float* __restrict__ b1, const float* __restrict__ b2,
             TOUT* __restrict__ C0, TOUT* __restrict__ C1, TOUT* __restrict__ C2,
             float s0, float s1, float s2)
{
  __shared__ __align__(16) u32 As32[128][32];                  // 16KB
  __shared__ __align__(16) u32 Bs32[DBUFB ? 2 : 1][128][32];   // 16/32KB

  constexpr bool AF32 = (sizeof(TIN) == 4);
  constexpr int K = 1024, NT = 16;

  const int seg = (NSEG == 1) ? 0 : (blockIdx.x >> 9);
  const int idb = (NSEG == 1) ? blockIdx.x : (blockIdx.x & 511);
  const TIN* A = seg == 0 ? A0 : (seg == 1 ? A1 : A2);
  const __hip_bfloat16* Wt = seg == 0 ? W0 : (seg == 1 ? W1 : W2);
  const float* bias = seg == 0 ? b0 : (seg == 1 ? b1 : b2);
  TOUT* C = seg == 0 ? C0 : (seg == 1 ? C1 : C2);
  const float scl = seg == 0 ? s0 : (seg == 1 ? s1 : s2);

  const int xcd = idb & 7, rr = idb >> 3;
  const int bx = rr & 7, by = xcd + 8 * (rr >> 3);
  const int m0 = by * 128, n0 = bx * 128;

  const int tid = threadIdx.x, lane = tid & 63, w = tid >> 6;
  const int l31 = lane & 31, hi = lane >> 5;
  const int wm = w >> 1, wn = w & 1;

  f32x16 acc[2][2] = {};

  const __hip_bfloat16* bptr[4];
  #pragma unroll
  for (int i = 0; i < 4; ++i) {
    const int off = (w * 4 + i) * 1024 + lane * 16;
    const int r = off >> 7;
    const int s = (off >> 4) & 7;
    bptr[i] = Wt + (size_t)(n0 + r) * K + (s ^ (r & 7)) * 8;
  }
  const TIN* aptr[4];
  const int arow = tid >> 3;
  const int acb  = (tid & 7) * 8;
  #pragma unroll
  for (int i = 0; i < 4; ++i) {
    if constexpr (!AF32) {
      const int off = (w * 4 + i) * 1024 + lane * 16;
      const int r = off >> 7;
      const int s = (off >> 4) & 7;
      aptr[i] = A + (size_t)(m0 + r) * K + (s ^ (r & 7)) * 8;
    } else {
      aptr[i] = nullptr;
    }
  }

  float4 ar[4][2];

  auto loadA_f32 = [&](int t) {
    #pragma unroll
    for (int p = 0; p < 4; ++p) {
      const float* ap = (const float*)A + (size_t)(m0 + arow + p * 32) * K + t * 64 + acb;
      ar[p][0] = *reinterpret_cast<const float4*>(ap);
      ar[p][1] = *reinterpret_cast<const float4*>(ap + 4);
    }
  };
  auto writeA_f32 = [&]() {
    #pragma unroll
    for (int p = 0; p < 4; ++p) {
      const int row = arow + p * 32;
      uint4 pk;
      pk.x = cvtpk(ar[p][0].x, ar[p][0].y);
      pk.y = cvtpk(ar[p][0].z, ar[p][0].w);
      pk.z = cvtpk(ar[p][1].x, ar[p][1].y);
      pk.w = cvtpk(ar[p][1].z, ar[p][1].w);
      *reinterpret_cast<uint4*>(&As32[row][((tid & 7) * 4) ^ ((row & 7) << 2)]) = pk;
    }
  };
  auto stageA_bf = [&](int t) {
    #pragma unroll
    for (int i = 0; i < 4; ++i)
      GLDS16((const __hip_bfloat16*)aptr[i] + t * 64, (char*)As32 + (w * 4 + i) * 1024);
  };
  auto stageB = [&](int buf, int t) {
    #pragma unroll
    for (int i = 0; i < 4; ++i)
      GLDS16(bptr[i] + t * 64, (char*)Bs32 + buf * 16384 + (w * 4 + i) * 1024);
  };

  int aoff[4][2], boff[4][2];
  #pragma unroll
  for (int kk = 0; kk < 4; ++kk) {
    #pragma unroll
    for (int mi = 0; mi < 2; ++mi) {
      const int r = wm * 64 + mi * 32 + l31;
      aoff[kk][mi] = r * 128 + (((kk * 2 + hi) ^ (r & 7)) << 4);
    }
    #pragma unroll
    for (int ni = 0; ni < 2; ++ni) {
      const int c = wn * 64 + ni * 32 + l31;
      boff[kk][ni] = c * 128 + (((kk * 2 + hi) ^ (c & 7)) << 4);
    }
  }

  if constexpr (AF32) { loadA_f32(0); writeA_f32(); }
  else                { stageA_bf(0); }
  stageB(0, 0);
  __syncthreads();

  for (int t = 0; t < NT; ++t) {
    const int cur = DBUFB ? (t & 1) : 0;
    const int nxt = DBUFB ? (cur ^ 1) : 0;

    if (t + 1 < NT) {
      if constexpr (DBUFB) stageB(nxt, t + 1);   // flies under compute(t)
      if constexpr (AF32)  loadA_f32(t + 1);
    }

    #pragma unroll
    for (int kk = 0; kk < 4; ++kk) {
      bf16x8 af[2], bfv[2];
      #pragma unroll
      for (int mi = 0; mi < 2; ++mi)
        af[mi] = *reinterpret_cast<const bf16x8*>((const char*)As32 + aoff[kk][mi]);
      #pragma unroll
      for (int ni = 0; ni < 2; ++ni)
        bfv[ni] = *reinterpret_cast<const bf16x8*>((const char*)Bs32 + cur * 16384 + boff[kk][ni]);
      #pragma unroll
      for (int mi = 0; mi < 2; ++mi)
        #pragma unroll
        for (int ni = 0; ni < 2; ++ni)
          acc[mi][ni] = __builtin_amdgcn_mfma_f32_32x32x16_bf16(af[mi], bfv[ni], acc[mi][ni], 0, 0, 0);
    }
    __syncthreads();   // reads of tile t done (drains vmcnt incl. prefetches)

    if (t + 1 < NT) {
      if constexpr (AF32) writeA_f32();
      else                stageA_bf(t + 1);
      if constexpr (!DBUFB) stageB(0, t + 1);
      __syncthreads();   // publish tile t+1
    }
  }

  #pragma unroll
  for (int ni = 0; ni < 2; ++ni) {
    const int col = n0 + wn * 64 + ni * 32 + l31;
    const float bv = bias[col];
    #pragma unroll
    for (int mi = 0; mi < 2; ++mi) {
      #pragma unroll
      for (int g = 0; g < 4; ++g)
        #pragma unroll
        for (int e = 0; e < 4; ++e) {
          const int row = m0 + wm * 64 + mi * 32 + g * 8 + hi * 4 + e;
          const float val = (acc[mi][ni][g * 4 + e] + bv) * scl;
          if constexpr (sizeof(TOUT) == 2)
            C[(size_t)row * DIM + col] = __float2bfloat16(val);
          else
            C[(size_t)row * DIM + col] = val;
        }
    }
  }
}

// ---------------------------------------------------------------------------
// Flash attention: 512 threads = 8 waves, QB=256 (32 q-rows/wave), 512 blocks.
// Static-max softmax (Q pre-scaled by 0.125*log2e -> exp2 direct). Deferred
// cross-lane l reduction (single shfl at end). Swapped MFMAs, cvt_pk +
// permlane32_swap P fragments, swizzled double-buffered K/V LDS.
// ---------------------------------------------------------------------------
__global__ __launch_bounds__(512, 4)
void flash_attn(const __hip_bfloat16* __restrict__ Qb,
                const __hip_bfloat16* __restrict__ Kb,
                const __hip_bfloat16* __restrict__ Vb,
                __hip_bfloat16* __restrict__ Ob)
{
  __shared__ __align__(16) u32 Ks32[2][64][32];
  __shared__ __align__(16) u32 Vt32[2][64][32];

  // 512 blocks = 8 xcd * 8 qb * 2 hh * 4 b ; h = xcd + 8*hh
  const int id  = blockIdx.x;
  const int xcd = id & 7;
  const int r_  = id >> 3;
  const int qb  = r_ & 7;
  const int hh  = (r_ >> 3) & 1;
  const int b   = r_ >> 4;
  const int h   = xcd + 8 * hh;

  const int tid = threadIdx.x, lane = tid & 63, w = tid >> 6;
  const int l31 = lane & 31, hi = lane >> 5;

  const size_t headoff = (size_t)h * HDIM;
  const int qrow = b * SEQ + qb * 256 + w * 32 + l31;   // this wave's q-row

  bf16x8 qf[4];
  #pragma unroll
  for (int dk = 0; dk < 4; ++dk)
    qf[dk] = *reinterpret_cast<const bf16x8*>(
      &Qb[(size_t)qrow * DIM + headoff + dk * 16 + hi * 8]);

  f32x16 accO[2] = {};
  float l_run = 0.f;

  const int skey = tid >> 3;
  const int sdq  = tid & 7;
  const int vkp  = tid >> 4;
  const int vdq  = tid & 15;
  const size_t kbase = (size_t)b * SEQ * DIM + headoff;

  uint4 kst;
  uint2 vst0, vst1;
  auto load_t = [&](int t) {
    const int kb = t * 64;
    kst = *reinterpret_cast<const uint4*>(&Kb[kbase + (size_t)(kb + skey) * DIM + sdq * 8]);
    const __hip_bfloat16* vp_ = &Vb[kbase + (size_t)(kb + vkp * 2) * DIM + vdq * 4];
    vst0 = *reinterpret_cast<const uint2*>(vp_);
    vst1 = *reinterpret_cast<const uint2*>(vp_ + DIM);
  };
  auto store_t = [&](int bb) {
    *reinterpret_cast<uint4*>(&Ks32[bb][skey][(sdq * 4) ^ swz4(skey)]) = kst;
    const unsigned short* a  = (const unsigned short*)&vst0;
    const unsigned short* bv = (const unsigned short*)&vst1;
    #pragma unroll
    for (int j = 0; j < 4; ++j) {
      const int row = vdq * 4 + j;
      Vt32[bb][row][vkp ^ swz4(row)] = (u32)a[j] | ((u32)bv[j] << 16);
    }
  };

  load_t(0); store_t(0); __syncthreads();

  for (int t = 0; t < SEQ / 64; ++t) {
    const int bb = t & 1;
    if (t < SEQ / 64 - 1) load_t(t + 1);

    // ---- S^T = K * Q^T (8 MFMA) ----
    f32x16 sacc[2] = {};
    __builtin_amdgcn_s_setprio(1);
    #pragma unroll
    for (int kt = 0; kt < 2; ++kt) {
      const int row = kt * 32 + l31;
      const int sk = swz4(row);
      #pragma unroll
      for (int dk = 0; dk < 4; ++dk) {
        bf16x8 kf = *reinterpret_cast<const bf16x8*>(&Ks32[bb][row][(dk * 8 + hi * 4) ^ sk]);
        sacc[kt] = __builtin_amdgcn_mfma_f32_32x32x16_bf16(kf, qf[dk], sacc[kt], 0, 0, 0);
      }
    }
    __builtin_amdgcn_s_setprio(0);

    // ---- static-max softmax: p = exp2(sacc) directly (Q pre-scaled) ----
    #pragma unroll
    for (int kt = 0; kt < 2; ++kt)
      #pragma unroll
      for (int r2 = 0; r2 < 16; ++r2)
        sacc[kt][r2] = __builtin_amdgcn_exp2f(sacc[kt][r2]);

    f32x16 ps = sacc[0] + sacc[1];
    float s8[8];
    #pragma unroll
    for (int i = 0; i < 8; ++i) s8[i] = ps[i] + ps[i + 8];
    l_run += ((s8[0] + s8[1]) + (s8[2] + s8[3])) + ((s8[4] + s8[5]) + (s8[6] + s8[7]));
    // cross-lane l reduction deferred to epilogue (lane pair l^32)

    // ---- P fragments ----
    u32 pf[4][4];
#define MAKE_PF(DST, P, B) do {                                            \
      u32 x1 = cvtpk(P[B+0], P[B+1]);                                      \
      u32 y1 = cvtpk(P[B+4], P[B+5]);                                      \
      u32 x2 = cvtpk(P[B+2], P[B+3]);                                      \
      u32 y2 = cvtpk(P[B+6], P[B+7]);                                      \
      auto s1_ = __builtin_amdgcn_permlane32_swap(x1, y1, false, false);   \
      auto s2_ = __builtin_amdgcn_permlane32_swap(x2, y2, false, false);   \
      DST[0] = (u32)s1_[0]; DST[1] = (u32)s2_[0];                          \
      DST[2] = (u32)s1_[1]; DST[3] = (u32)s2_[1];                          \
    } while (0)
    MAKE_PF(pf[0], sacc[0], 0);
    MAKE_PF(pf[1], sacc[0], 8);
    MAKE_PF(pf[2], sacc[1], 0);
    MAKE_PF(pf[3], sacc[1], 8);
#undef MAKE_PF

    // ---- O^T += V^T * P^T (8 MFMA) ----
    __builtin_amdgcn_s_setprio(1);
    #pragma unroll
    for (int dt = 0; dt < 2; ++dt) {
      const int row = dt * 32 + l31;
      const int sk = swz4(row);
      #pragma unroll
      for (int kf = 0; kf < 4; ++kf) {
        bf16x8 vf = *reinterpret_cast<const bf16x8*>(&Vt32[bb][row][(kf * 8 + hi * 4) ^ sk]);
        union { u32 u[4]; bf16x8 v; } pu;
        pu.u[0] = pf[kf][0]; pu.u[1] = pf[kf][1];
        pu.u[2] = pf[kf][2]; pu.u[3] = pf[kf][3];
        accO[dt] = __builtin_amdgcn_mfma_f32_32x32x16_bf16(vf, pu.v, accO[dt], 0, 0, 0);
      }
    }
    __builtin_amdgcn_s_setprio(0);

    if (t < SEQ / 64 - 1) store_t(bb ^ 1);
    __syncthreads();
  }

  // ---- write O (finish l reduction: pair lane l^32 holds other 32 keys) ----
  l_run += __shfl_xor(l_run, 32);
  const float inv = 1.f / l_run;
  const size_t rowbase = (size_t)qrow * DIM + headoff;
  #pragma unroll
  for (int dt = 0; dt < 2; ++dt)
    #pragma unroll
    for (int g = 0; g < 4; ++g) {
      ushort4 o;
      o.x = f2bfu(accO[dt][g * 4 + 0] * inv);
      o.y = f2bfu(accO[dt][g * 4 + 1] * inv);
      o.z = f2bfu(accO[dt][g * 4 + 2] * inv);
      o.w = f2bfu(accO[dt][g * 4 + 3] * inv);
      *reinterpret_cast<ushort4*>(&Ob[rowbase + dt * 32 + g * 8 + hi * 4]) = o;
    }
}

// ---------------------------------------------------------------------------
extern "C" void kernel_launch(void* const* d_in, const int* in_sizes, int n_in,
                              void* d_out, int out_size, void* d_ws, size_t ws_size,
                              hipStream_t stream)
{
  const float* q  = (const float*)d_in[0];
  const float* k  = (const float*)d_in[1];
  const float* v  = (const float*)d_in[2];
  const float* wq = (const float*)d_in[3];
  const float* bq = (const float*)d_in[4];
  const float* wk = (const float*)d_in[5];
  const float* bk = (const float*)d_in[6];
  const float* wv = (const float*)d_in[7];
  const float* bv = (const float*)d_in[8];
  const float* wo = (const float*)d_in[9];
  const float* bo = (const float*)d_in[10];

  const size_t MN = (size_t)BATCH * SEQ * DIM;   // 8388608
  const size_t KK = (size_t)DIM * DIM;           // 1048576
  const float  C1 = 0.125f * 1.44269504f;        // softmax scale * log2(e)

  __hip_bfloat16* Qb = (__hip_bfloat16*)d_ws;
  __hip_bfloat16* Kb = Qb + MN;
  __hip_bfloat16* Vb = Kb + MN;
  __hip_bfloat16* S3 = Vb + MN;     // 4th 16MB slot
  __hip_bfloat16* WtQ = S3;         // weights live here until attention
  __hip_bfloat16* WtK = S3 + KK;
  __hip_bfloat16* WtV = S3 + 2 * KK;
  __hip_bfloat16* Ob  = S3;         // attention output overwrites Wt (dead)
  __hip_bfloat16* WtO = (__hip_bfloat16*)d_ws;  // into Qb slot after attention

  wtrans<<<768, 256, 0, stream>>>(wq, wk, wv, WtQ, WtK, WtV);

  gemm1ph<float, __hip_bfloat16, 3, true><<<1536, 256, 0, stream>>>(
      q, k, v, WtQ, WtK, WtV, bq, bk, bv, Qb, Kb, Vb, C1, 1.0f, 1.0f);

  flash_attn<<<512, 512, 0, stream>>>(Qb, Kb, Vb, Ob);

  wtrans<<<256, 256, 0, stream>>>(wo, wo, wo, WtO, WtO, WtO);

  gemm1ph<__hip_bfloat16, float, 1, false><<<512, 256, 0, stream>>>(
      Ob, Ob, Ob, WtO, WtO, WtO, bo, bo, bo,
      (float*)d_out, (float*)d_out, (float*)d_out, 1.0f, 1.0f, 1.0f);
}

// Round 12
// 192.580 us; speedup vs baseline: 1.0729x; 1.0144x over previous
//
#include <hip/hip_runtime.h>
#include <hip/hip_bf16.h>

#define BATCH 4
#define SEQ   2048
#define DIM   1024
#define NHEAD 16
#define HDIM  64

typedef __bf16    bf16x8 __attribute__((ext_vector_type(8)));
typedef float     f32x16 __attribute__((ext_vector_type(16)));
typedef unsigned  u32;

__device__ __forceinline__ unsigned short f2bfu(float x) {
  union { __hip_bfloat16 b; unsigned short u; } c; c.b = __float2bfloat16(x); return c.u;
}
__device__ __forceinline__ u32 cvtpk(float lo, float hi) {
  u32 r; asm("v_cvt_pk_bf16_f32 %0, %1, %2" : "=v"(r) : "v"(lo), "v"(hi)); return r;
}
__device__ __forceinline__ int swz4(int row) {
  return ((row & 7) ^ ((row >> 3) & 7)) << 2;
}
__device__ __forceinline__ int swz7(int row) {
  return (row & 7) ^ ((row >> 3) & 7);
}

// async 16B global->LDS (LDS dest: wave-uniform base; HW adds lane*16)
#define GLDS16(GP, LP)                                                         \
  __builtin_amdgcn_global_load_lds(                                            \
      (const __attribute__((address_space(1))) void*)(GP),                     \
      (__attribute__((address_space(3))) void*)(LP), 16, 0, 0)

// ---------------------------------------------------------------------------
// Weight transpose+convert: Wt[n][k] = bf16(W[k][n]). 64x64 tile per block.
// ---------------------------------------------------------------------------
__global__ __launch_bounds__(256)
void wtrans(const float* __restrict__ w0, const float* __restrict__ w1,
            const float* __restrict__ w2,
            __hip_bfloat16* __restrict__ t0, __hip_bfloat16* __restrict__ t1,
            __hip_bfloat16* __restrict__ t2)
{
  __shared__ float T[64][68];
  const int mat  = blockIdx.x >> 8;
  const int tile = blockIdx.x & 255;
  const float* W = mat == 0 ? w0 : (mat == 1 ? w1 : w2);
  __hip_bfloat16* Wt = mat == 0 ? t0 : (mat == 1 ? t1 : t2);
  const int k0 = (tile >> 4) * 64, n0 = (tile & 15) * 64;
  const int tid = threadIdx.x;
  const int r = tid >> 2, cq = (tid & 3) * 16;
  #pragma unroll
  for (int j = 0; j < 4; ++j) {
    const float4 v = *reinterpret_cast<const float4*>(&W[(size_t)(k0 + r) * DIM + n0 + cq + j * 4]);
    T[r][cq + j * 4 + 0] = v.x; T[r][cq + j * 4 + 1] = v.y;
    T[r][cq + j * 4 + 2] = v.z; T[r][cq + j * 4 + 3] = v.w;
  }
  __syncthreads();
  u32 o[8];
  #pragma unroll
  for (int j = 0; j < 8; ++j)
    o[j] = cvtpk(T[cq + 2 * j][r], T[cq + 2 * j + 1][r]);
  *reinterpret_cast<uint4*>(&Wt[(size_t)(n0 + r) * DIM + k0 + cq + 0]) = make_uint4(o[0], o[1], o[2], o[3]);
  *reinterpret_cast<uint4*>(&Wt[(size_t)(n0 + r) * DIM + k0 + cq + 8]) = make_uint4(o[4], o[5], o[6], o[7]);
}

// ---------------------------------------------------------------------------
// 1-phase GEMM, bf16-only 32KB LDS (single-buffered, r9-verified config).
// fp32 A: reg-stage (loads issued before compute; cvt+ds_write after barrier,
// AFTER the async GLDS16 issues so their latency hides under the VALU work).
// bf16 A: GLDS16 direct. B (bf16 Wt[N][K]): GLDS16, pre-swizzled source.
// 128x128 tile, BK=64, 4 waves 2x2 of 64x64, 32x32x16 MFMA.
// ---------------------------------------------------------------------------
template<typename TIN, typename TOUT, int NSEG>
__global__ __launch_bounds__(256, 2)
void gemm1ph(const TIN* __restrict__ A0, const TIN* __restrict__ A1, const TIN* __restrict__ A2,
             const __hip_bfloat16* __restrict__ W0, const __hip_bfloat16* __restrict__ W1,
             const __hip_bfloat16* __restrict__ W2,
             const float* __restrict__ b0, const float* __restrict__ b1, const float* __restrict__ b2,
             TOUT* __restrict__ C0, TOUT* __restrict__ C1, TOUT* __restrict__ C2,
             float s0, float s1, float s2)
{
  __shared__ __align__(16) u32 As32[128][32];   // bf16 [row][k-pairs], swizzled (16KB)
  __shared__ __align__(16) u32 Bs32[128][32];   // bf16 [col][k-pairs], swizzled (16KB)

  constexpr bool AF32 = (sizeof(TIN) == 4);
  constexpr int K = 1024, NT = 16;

  const int seg = (NSEG == 1) ? 0 : (blockIdx.x >> 9);
  const int idb = (NSEG == 1) ? blockIdx.x : (blockIdx.x & 511);
  const TIN* A = seg == 0 ? A0 : (seg == 1 ? A1 : A2);
  const __hip_bfloat16* Wt = seg == 0 ? W0 : (seg == 1 ? W1 : W2);
  const float* bias = seg == 0 ? b0 : (seg == 1 ? b1 : b2);
  TOUT* C = seg == 0 ? C0 : (seg == 1 ? C1 : C2);
  const float scl = seg == 0 ? s0 : (seg == 1 ? s1 : s2);

  const int xcd = idb & 7, rr = idb >> 3;
  const int bx = rr & 7, by = xcd + 8 * (rr >> 3);
  const int m0 = by * 128, n0 = bx * 128;

  const int tid = threadIdx.x, lane = tid & 63, w = tid >> 6;
  const int l31 = lane & 31, hi = lane >> 5;
  const int wm = w >> 1, wn = w & 1;

  f32x16 acc[2][2] = {};

  const __hip_bfloat16* bptr[4];
  #pragma unroll
  for (int i = 0; i < 4; ++i) {
    const int off = (w * 4 + i) * 1024 + lane * 16;
    const int r = off >> 7;
    const int s = (off >> 4) & 7;
    bptr[i] = Wt + (size_t)(n0 + r) * K + (s ^ (r & 7)) * 8;
  }
  const TIN* aptr[4];
  const int arow = tid >> 3;
  const int acb  = (tid & 7) * 8;
  #pragma unroll
  for (int i = 0; i < 4; ++i) {
    if constexpr (!AF32) {
      const int off = (w * 4 + i) * 1024 + lane * 16;
      const int r = off >> 7;
      const int s = (off >> 4) & 7;
      aptr[i] = A + (size_t)(m0 + r) * K + (s ^ (r & 7)) * 8;
    } else {
      aptr[i] = nullptr;
    }
  }

  float4 ar[4][2];

  auto loadA_f32 = [&](int t) {
    #pragma unroll
    for (int p = 0; p < 4; ++p) {
      const float* ap = (const float*)A + (size_t)(m0 + arow + p * 32) * K + t * 64 + acb;
      ar[p][0] = *reinterpret_cast<const float4*>(ap);
      ar[p][1] = *reinterpret_cast<const float4*>(ap + 4);
    }
  };
  auto writeA_f32 = [&]() {
    #pragma unroll
    for (int p = 0; p < 4; ++p) {
      const int row = arow + p * 32;
      uint4 pk;
      pk.x = cvtpk(ar[p][0].x, ar[p][0].y);
      pk.y = cvtpk(ar[p][0].z, ar[p][0].w);
      pk.z = cvtpk(ar[p][1].x, ar[p][1].y);
      pk.w = cvtpk(ar[p][1].z, ar[p][1].w);
      *reinterpret_cast<uint4*>(&As32[row][((tid & 7) * 4) ^ ((row & 7) << 2)]) = pk;
    }
  };
  auto stageA_bf = [&](int t) {
    #pragma unroll
    for (int i = 0; i < 4; ++i)
      GLDS16((const __hip_bfloat16*)aptr[i] + t * 64, (char*)As32 + (w * 4 + i) * 1024);
  };
  auto stageB = [&](int t) {
    #pragma unroll
    for (int i = 0; i < 4; ++i)
      GLDS16(bptr[i] + t * 64, (char*)Bs32 + (w * 4 + i) * 1024);
  };

  int aoff[4][2], boff[4][2];
  #pragma unroll
  for (int kk = 0; kk < 4; ++kk) {
    #pragma unroll
    for (int mi = 0; mi < 2; ++mi) {
      const int r = wm * 64 + mi * 32 + l31;
      aoff[kk][mi] = r * 128 + (((kk * 2 + hi) ^ (r & 7)) << 4);
    }
    #pragma unroll
    for (int ni = 0; ni < 2; ++ni) {
      const int c = wn * 64 + ni * 32 + l31;
      boff[kk][ni] = c * 128 + (((kk * 2 + hi) ^ (c & 7)) << 4);
    }
  }

  if constexpr (AF32) { loadA_f32(0); writeA_f32(); }
  else                { stageA_bf(0); }
  stageB(0);
  __syncthreads();

  for (int t = 0; t < NT; ++t) {
    if (t + 1 < NT) { if constexpr (AF32) loadA_f32(t + 1); }

    #pragma unroll
    for (int kk = 0; kk < 4; ++kk) {
      bf16x8 af[2], bfv[2];
      #pragma unroll
      for (int mi = 0; mi < 2; ++mi)
        af[mi] = *reinterpret_cast<const bf16x8*>((const char*)As32 + aoff[kk][mi]);
      #pragma unroll
      for (int ni = 0; ni < 2; ++ni)
        bfv[ni] = *reinterpret_cast<const bf16x8*>((const char*)Bs32 + boff[kk][ni]);
      #pragma unroll
      for (int mi = 0; mi < 2; ++mi)
        #pragma unroll
        for (int ni = 0; ni < 2; ++ni)
          acc[mi][ni] = __builtin_amdgcn_mfma_f32_32x32x16_bf16(af[mi], bfv[ni], acc[mi][ni], 0, 0, 0);
    }
    __syncthreads();   // all reads of tile t done

    if (t + 1 < NT) {
      // async GLDS16 issues first: latency hides under writeA's VALU work
      stageB(t + 1);
      if constexpr (AF32) writeA_f32();
      else                stageA_bf(t + 1);
      __syncthreads();   // publish tile t+1
    }
  }

  #pragma unroll
  for (int ni = 0; ni < 2; ++ni) {
    const int col = n0 + wn * 64 + ni * 32 + l31;
    const float bv = bias[col];
    #pragma unroll
    for (int mi = 0; mi < 2; ++mi) {
      #pragma unroll
      for (int g = 0; g < 4; ++g)
        #pragma unroll
        for (int e = 0; e < 4; ++e) {
          const int row = m0 + wm * 64 + mi * 32 + g * 8 + hi * 4 + e;
          const float val = (acc[mi][ni][g * 4 + e] + bv) * scl;
          if constexpr (sizeof(TOUT) == 2)
            C[(size_t)row * DIM + col] = __float2bfloat16(val);
          else
            C[(size_t)row * DIM + col] = val;
        }
    }
  }
}

// ---------------------------------------------------------------------------
// Flash attention: 512 threads = 8 waves, QB=256 (32 q-rows/wave), 512 blocks.
// Static-max softmax (Q pre-scaled by 0.125*log2e -> exp2 direct). Deferred
// cross-lane l reduction. K staged via GLDS16 with PRE-SWIZZLED source
// (linear LDS dest; double-XOR cancels at read). V reg-staged transpose-pack.
// ---------------------------------------------------------------------------
__global__ __launch_bounds__(512, 4)
void flash_attn(const __hip_bfloat16* __restrict__ Qb,
                const __hip_bfloat16* __restrict__ Kb,
                const __hip_bfloat16* __restrict__ Vb,
                __hip_bfloat16* __restrict__ Ob)
{
  __shared__ __align__(16) u32 Ks32[2][64][32];
  __shared__ __align__(16) u32 Vt32[2][64][32];

  // 512 blocks = 8 xcd * 8 qb * 2 hh * 4 b ; h = xcd + 8*hh
  const int id  = blockIdx.x;
  const int xcd = id & 7;
  const int r_  = id >> 3;
  const int qb  = r_ & 7;
  const int hh  = (r_ >> 3) & 1;
  const int b   = r_ >> 4;
  const int h   = xcd + 8 * hh;

  const int tid = threadIdx.x, lane = tid & 63, w = tid >> 6;
  const int l31 = lane & 31, hi = lane >> 5;

  const size_t headoff = (size_t)h * HDIM;
  const int qrow = b * SEQ + qb * 256 + w * 32 + l31;   // this wave's q-row

  bf16x8 qf[4];
  #pragma unroll
  for (int dk = 0; dk < 4; ++dk)
    qf[dk] = *reinterpret_cast<const bf16x8*>(
      &Qb[(size_t)qrow * DIM + headoff + dk * 16 + hi * 8]);

  f32x16 accO[2] = {};
  float l_run = 0.f;

  const size_t kbase = (size_t)b * SEQ * DIM + headoff;

  // K GLDS16: thread covers row kr = tid>>3, granule kg = tid&7 (linear dest);
  // source pre-swizzled so LDS granule G of row r holds global granule G^swz7(r).
  const int kr = tid >> 3, kg = tid & 7;
  const __hip_bfloat16* kGptr = Kb + kbase + (size_t)kr * DIM + (kg ^ swz7(kr)) * 8;
  char* const kLbase = (char*)Ks32 + w * 1024;   // + nb*8192 per tile

  // V reg-staging mappings
  const int vkp = tid >> 4;
  const int vdq = tid & 15;
  uint2 vst0, vst1;

  auto loadV = [&](int t) {
    const __hip_bfloat16* vp_ = &Vb[kbase + (size_t)(t * 64 + vkp * 2) * DIM + vdq * 4];
    vst0 = *reinterpret_cast<const uint2*>(vp_);
    vst1 = *reinterpret_cast<const uint2*>(vp_ + DIM);
  };
  auto stageK = [&](int nb, int t) {
    GLDS16(kGptr + (size_t)(t * 64) * DIM, kLbase + nb * 8192);
  };
  auto storeV = [&](int nb) {
    const unsigned short* a  = (const unsigned short*)&vst0;
    const unsigned short* bv = (const unsigned short*)&vst1;
    #pragma unroll
    for (int j = 0; j < 4; ++j) {
      const int row = vdq * 4 + j;
      Vt32[nb][row][vkp ^ swz4(row)] = (u32)a[j] | ((u32)bv[j] << 16);
    }
  };

  stageK(0, 0); loadV(0); storeV(0); __syncthreads();

  for (int t = 0; t < SEQ / 64; ++t) {
    const int bb = t & 1;
    if (t < SEQ / 64 - 1) { stageK(bb ^ 1, t + 1); loadV(t + 1); }

    // ---- S^T = K * Q^T (8 MFMA) ----
    f32x16 sacc[2] = {};
    __builtin_amdgcn_s_setprio(1);
    #pragma unroll
    for (int kt = 0; kt < 2; ++kt) {
      const int row = kt * 32 + l31;
      const int sk = swz4(row);
      #pragma unroll
      for (int dk = 0; dk < 4; ++dk) {
        bf16x8 kf = *reinterpret_cast<const bf16x8*>(&Ks32[bb][row][(dk * 8 + hi * 4) ^ sk]);
        sacc[kt] = __builtin_amdgcn_mfma_f32_32x32x16_bf16(kf, qf[dk], sacc[kt], 0, 0, 0);
      }
    }
    __builtin_amdgcn_s_setprio(0);

    // ---- static-max softmax: p = exp2(sacc) directly ----
    #pragma unroll
    for (int kt = 0; kt < 2; ++kt)
      #pragma unroll
      for (int r2 = 0; r2 < 16; ++r2)
        sacc[kt][r2] = __builtin_amdgcn_exp2f(sacc[kt][r2]);

    f32x16 ps = sacc[0] + sacc[1];
    float s8[8];
    #pragma unroll
    for (int i = 0; i < 8; ++i) s8[i] = ps[i] + ps[i + 8];
    l_run += ((s8[0] + s8[1]) + (s8[2] + s8[3])) + ((s8[4] + s8[5]) + (s8[6] + s8[7]));

    // ---- P fragments ----
    u32 pf[4][4];
#define MAKE_PF(DST, P, B) do {                                            \
      u32 x1 = cvtpk(P[B+0], P[B+1]);                                      \
      u32 y1 = cvtpk(P[B+4], P[B+5]);                                      \
      u32 x2 = cvtpk(P[B+2], P[B+3]);                                      \
      u32 y2 = cvtpk(P[B+6], P[B+7]);                                      \
      auto s1_ = __builtin_amdgcn_permlane32_swap(x1, y1, false, false);   \
      auto s2_ = __builtin_amdgcn_permlane32_swap(x2, y2, false, false);   \
      DST[0] = (u32)s1_[0]; DST[1] = (u32)s2_[0];                          \
      DST[2] = (u32)s1_[1]; DST[3] = (u32)s2_[1];                          \
    } while (0)
    MAKE_PF(pf[0], sacc[0], 0);
    MAKE_PF(pf[1], sacc[0], 8);
    MAKE_PF(pf[2], sacc[1], 0);
    MAKE_PF(pf[3], sacc[1], 8);
#undef MAKE_PF

    // ---- O^T += V^T * P^T (8 MFMA) ----
    __builtin_amdgcn_s_setprio(1);
    #pragma unroll
    for (int dt = 0; dt < 2; ++dt) {
      const int row = dt * 32 + l31;
      const int sk = swz4(row);
      #pragma unroll
      for (int kf = 0; kf < 4; ++kf) {
        bf16x8 vf = *reinterpret_cast<const bf16x8*>(&Vt32[bb][row][(kf * 8 + hi * 4) ^ sk]);
        union { u32 u[4]; bf16x8 v; } pu;
        pu.u[0] = pf[kf][0]; pu.u[1] = pf[kf][1];
        pu.u[2] = pf[kf][2]; pu.u[3] = pf[kf][3];
        accO[dt] = __builtin_amdgcn_mfma_f32_32x32x16_bf16(vf, pu.v, accO[dt], 0, 0, 0);
      }
    }
    __builtin_amdgcn_s_setprio(0);

    if (t < SEQ / 64 - 1) storeV(bb ^ 1);
    __syncthreads();   // drains K GLDS16 (vmcnt) + V ds_writes; publishes bb^1
  }

  // ---- write O (finish l reduction: lane l^32 holds the other 32 keys) ----
  l_run += __shfl_xor(l_run, 32);
  const float inv = 1.f / l_run;
  const size_t rowbase = (size_t)qrow * DIM + headoff;
  #pragma unroll
  for (int dt = 0; dt < 2; ++dt)
    #pragma unroll
    for (int g = 0; g < 4; ++g) {
      ushort4 o;
      o.x = f2bfu(accO[dt][g * 4 + 0] * inv);
      o.y = f2bfu(accO[dt][g * 4 + 1] * inv);
      o.z = f2bfu(accO[dt][g * 4 + 2] * inv);
      o.w = f2bfu(accO[dt][g * 4 + 3] * inv);
      *reinterpret_cast<ushort4*>(&Ob[rowbase + dt * 32 + g * 8 + hi * 4]) = o;
    }
}

// ---------------------------------------------------------------------------
extern "C" void kernel_launch(void* const* d_in, const int* in_sizes, int n_in,
                              void* d_out, int out_size, void* d_ws, size_t ws_size,
                              hipStream_t stream)
{
  const float* q  = (const float*)d_in[0];
  const float* k  = (const float*)d_in[1];
  const float* v  = (const float*)d_in[2];
  const float* wq = (const float*)d_in[3];
  const float* bq = (const float*)d_in[4];
  const float* wk = (const float*)d_in[5];
  const float* bk = (const float*)d_in[6];
  const float* wv = (const float*)d_in[7];
  const float* bv = (const float*)d_in[8];
  const float* wo = (const float*)d_in[9];
  const float* bo = (const float*)d_in[10];

  const size_t MN = (size_t)BATCH * SEQ * DIM;   // 8388608
  const size_t KK = (size_t)DIM * DIM;           // 1048576
  const float  C1 = 0.125f * 1.44269504f;        // softmax scale * log2(e)

  __hip_bfloat16* Qb = (__hip_bfloat16*)d_ws;
  __hip_bfloat16* Kb = Qb + MN;
  __hip_bfloat16* Vb = Kb + MN;
  __hip_bfloat16* S3 = Vb + MN;     // 4th 16MB slot
  __hip_bfloat16* WtQ = S3;         // weights live here until attention
  __hip_bfloat16* WtK = S3 + KK;
  __hip_bfloat16* WtV = S3 + 2 * KK;
  __hip_bfloat16* Ob  = S3;         // attention output overwrites Wt (dead)
  __hip_bfloat16* WtO = (__hip_bfloat16*)d_ws;  // into Qb slot after attention

  wtrans<<<768, 256, 0, stream>>>(wq, wk, wv, WtQ, WtK, WtV);

  gemm1ph<float, __hip_bfloat16, 3><<<1536, 256, 0, stream>>>(
      q, k, v, WtQ, WtK, WtV, bq, bk, bv, Qb, Kb, Vb, C1, 1.0f, 1.0f);

  flash_attn<<<512, 512, 0, stream>>>(Qb, Kb, Vb, Ob);

  wtrans<<<256, 256, 0, stream>>>(wo, wo, wo, WtO, WtO, WtO);

  gemm1ph<__hip_bfloat16, float, 1><<<512, 256, 0, stream>>>(
      Ob, Ob, Ob, WtO, WtO, WtO, bo, bo, bo,
      (float*)d_out, (float*)d_out, (float*)d_out, 1.0f, 1.0f, 1.0f);
}

// Round 13
// 187.267 us; speedup vs baseline: 1.1034x; 1.0284x over previous
//
#include <hip/hip_runtime.h>
#include <hip/hip_bf16.h>

#define BATCH 4
#define SEQ   2048
#define DIM   1024
#define NHEAD 16
#define HDIM  64

typedef __bf16    bf16x8 __attribute__((ext_vector_type(8)));
typedef float     f32x16 __attribute__((ext_vector_type(16)));
typedef unsigned  u32;

__device__ __forceinline__ unsigned short f2bfu(float x) {
  union { __hip_bfloat16 b; unsigned short u; } c; c.b = __float2bfloat16(x); return c.u;
}
__device__ __forceinline__ u32 cvtpk(float lo, float hi) {
  u32 r; asm("v_cvt_pk_bf16_f32 %0, %1, %2" : "=v"(r) : "v"(lo), "v"(hi)); return r;
}
__device__ __forceinline__ int swz4(int row) {
  return ((row & 7) ^ ((row >> 3) & 7)) << 2;
}
__device__ __forceinline__ int swz7(int row) {
  return (row & 7) ^ ((row >> 3) & 7);
}

// async 16B global->LDS (LDS dest: wave-uniform base; HW adds lane*16)
#define GLDS16(GP, LP)                                                         \
  __builtin_amdgcn_global_load_lds(                                            \
      (const __attribute__((address_space(1))) void*)(GP),                     \
      (__attribute__((address_space(3))) void*)(LP), 16, 0, 0)

// raw barrier + counted waits (T4): compiler fences via "memory" clobber
#define WAITCNT(S) asm volatile("s_waitcnt " S ::: "memory")
#define SBAR()     do { __builtin_amdgcn_s_barrier();                          \
                        asm volatile("" ::: "memory"); } while (0)

// ---------------------------------------------------------------------------
// Weight transpose+convert: Wt[n][k] = bf16(W[k][n]). 64x64 tile per block.
// ---------------------------------------------------------------------------
__global__ __launch_bounds__(256)
void wtrans(const float* __restrict__ w0, const float* __restrict__ w1,
            const float* __restrict__ w2,
            __hip_bfloat16* __restrict__ t0, __hip_bfloat16* __restrict__ t1,
            __hip_bfloat16* __restrict__ t2)
{
  __shared__ float T[64][68];
  const int mat  = blockIdx.x >> 8;
  const int tile = blockIdx.x & 255;
  const float* W = mat == 0 ? w0 : (mat == 1 ? w1 : w2);
  __hip_bfloat16* Wt = mat == 0 ? t0 : (mat == 1 ? t1 : t2);
  const int k0 = (tile >> 4) * 64, n0 = (tile & 15) * 64;
  const int tid = threadIdx.x;
  const int r = tid >> 2, cq = (tid & 3) * 16;
  #pragma unroll
  for (int j = 0; j < 4; ++j) {
    const float4 v = *reinterpret_cast<const float4*>(&W[(size_t)(k0 + r) * DIM + n0 + cq + j * 4]);
    T[r][cq + j * 4 + 0] = v.x; T[r][cq + j * 4 + 1] = v.y;
    T[r][cq + j * 4 + 2] = v.z; T[r][cq + j * 4 + 3] = v.w;
  }
  __syncthreads();
  u32 o[8];
  #pragma unroll
  for (int j = 0; j < 8; ++j)
    o[j] = cvtpk(T[cq + 2 * j][r], T[cq + 2 * j + 1][r]);
  *reinterpret_cast<uint4*>(&Wt[(size_t)(n0 + r) * DIM + k0 + cq + 0]) = make_uint4(o[0], o[1], o[2], o[3]);
  *reinterpret_cast<uint4*>(&Wt[(size_t)(n0 + r) * DIM + k0 + cq + 8]) = make_uint4(o[4], o[5], o[6], o[7]);
}

// ---------------------------------------------------------------------------
// 1-phase GEMM, bf16-only 32KB LDS. fp32-A path: counted-vmcnt pipeline —
// loadA(t+2) issued in stage(t) right after writeA frees the registers;
// raw s_barrier with vmcnt(8) keeps the 8 A-loads in flight across the
// barrier (T4). bf16-A path: unchanged GLDS16 + __syncthreads structure.
// 128x128 tile, BK=64, 4 waves 2x2 of 64x64, 32x32x16 MFMA.
// ---------------------------------------------------------------------------
template<typename TIN, typename TOUT, int NSEG>
__global__ __launch_bounds__(256, 2)
void gemm1ph(const TIN* __restrict__ A0, const TIN* __restrict__ A1, const TIN* __restrict__ A2,
             const __hip_bfloat16* __restrict__ W0, const __hip_bfloat16* __restrict__ W1,
             const __hip_bfloat16* __restrict__ W2,
             const float* __restrict__ b0, const float* __restrict__ b1, const float* __restrict__ b2,
             TOUT* __restrict__ C0, TOUT* __restrict__ C1, TOUT* __restrict__ C2,
             float s0, float s1, float s2)
{
  __shared__ __align__(16) u32 As32[128][32];   // bf16 [row][k-pairs], swizzled (16KB)
  __shared__ __align__(16) u32 Bs32[128][32];   // bf16 [col][k-pairs], swizzled (16KB)

  constexpr bool AF32 = (sizeof(TIN) == 4);
  constexpr int K = 1024, NT = 16;

  const int seg = (NSEG == 1) ? 0 : (blockIdx.x >> 9);
  const int idb = (NSEG == 1) ? blockIdx.x : (blockIdx.x & 511);
  const TIN* A = seg == 0 ? A0 : (seg == 1 ? A1 : A2);
  const __hip_bfloat16* Wt = seg == 0 ? W0 : (seg == 1 ? W1 : W2);
  const float* bias = seg == 0 ? b0 : (seg == 1 ? b1 : b2);
  TOUT* C = seg == 0 ? C0 : (seg == 1 ? C1 : C2);
  const float scl = seg == 0 ? s0 : (seg == 1 ? s1 : s2);

  const int xcd = idb & 7, rr = idb >> 3;
  const int bx = rr & 7, by = xcd + 8 * (rr >> 3);
  const int m0 = by * 128, n0 = bx * 128;

  const int tid = threadIdx.x, lane = tid & 63, w = tid >> 6;
  const int l31 = lane & 31, hi = lane >> 5;
  const int wm = w >> 1, wn = w & 1;

  f32x16 acc[2][2] = {};

  const __hip_bfloat16* bptr[4];
  #pragma unroll
  for (int i = 0; i < 4; ++i) {
    const int off = (w * 4 + i) * 1024 + lane * 16;
    const int r = off >> 7;
    const int s = (off >> 4) & 7;
    bptr[i] = Wt + (size_t)(n0 + r) * K + (s ^ (r & 7)) * 8;
  }
  const TIN* aptr[4];
  const int arow = tid >> 3;
  const int acb  = (tid & 7) * 8;
  #pragma unroll
  for (int i = 0; i < 4; ++i) {
    if constexpr (!AF32) {
      const int off = (w * 4 + i) * 1024 + lane * 16;
      const int r = off >> 7;
      const int s = (off >> 4) & 7;
      aptr[i] = A + (size_t)(m0 + r) * K + (s ^ (r & 7)) * 8;
    } else {
      aptr[i] = nullptr;
    }
  }

  float4 ar[4][2];

  auto loadA_f32 = [&](int t) {
    #pragma unroll
    for (int p = 0; p < 4; ++p) {
      const float* ap = (const float*)A + (size_t)(m0 + arow + p * 32) * K + t * 64 + acb;
      ar[p][0] = *reinterpret_cast<const float4*>(ap);
      ar[p][1] = *reinterpret_cast<const float4*>(ap + 4);
    }
  };
  auto writeA_f32 = [&]() {
    #pragma unroll
    for (int p = 0; p < 4; ++p) {
      const int row = arow + p * 32;
      uint4 pk;
      pk.x = cvtpk(ar[p][0].x, ar[p][0].y);
      pk.y = cvtpk(ar[p][0].z, ar[p][0].w);
      pk.z = cvtpk(ar[p][1].x, ar[p][1].y);
      pk.w = cvtpk(ar[p][1].z, ar[p][1].w);
      *reinterpret_cast<uint4*>(&As32[row][((tid & 7) * 4) ^ ((row & 7) << 2)]) = pk;
    }
  };
  auto stageA_bf = [&](int t) {
    #pragma unroll
    for (int i = 0; i < 4; ++i)
      GLDS16((const __hip_bfloat16*)aptr[i] + t * 64, (char*)As32 + (w * 4 + i) * 1024);
  };
  auto stageB = [&](int t) {
    #pragma unroll
    for (int i = 0; i < 4; ++i)
      GLDS16(bptr[i] + t * 64, (char*)Bs32 + (w * 4 + i) * 1024);
  };

  int aoff[4][2], boff[4][2];
  #pragma unroll
  for (int kk = 0; kk < 4; ++kk) {
    #pragma unroll
    for (int mi = 0; mi < 2; ++mi) {
      const int r = wm * 64 + mi * 32 + l31;
      aoff[kk][mi] = r * 128 + (((kk * 2 + hi) ^ (r & 7)) << 4);
    }
    #pragma unroll
    for (int ni = 0; ni < 2; ++ni) {
      const int c = wn * 64 + ni * 32 + l31;
      boff[kk][ni] = c * 128 + (((kk * 2 + hi) ^ (c & 7)) << 4);
    }
  }

  auto compute_tile = [&]() {
    #pragma unroll
    for (int kk = 0; kk < 4; ++kk) {
      bf16x8 af[2], bfv[2];
      #pragma unroll
      for (int mi = 0; mi < 2; ++mi)
        af[mi] = *reinterpret_cast<const bf16x8*>((const char*)As32 + aoff[kk][mi]);
      #pragma unroll
      for (int ni = 0; ni < 2; ++ni)
        bfv[ni] = *reinterpret_cast<const bf16x8*>((const char*)Bs32 + boff[kk][ni]);
      #pragma unroll
      for (int mi = 0; mi < 2; ++mi)
        #pragma unroll
        for (int ni = 0; ni < 2; ++ni)
          acc[mi][ni] = __builtin_amdgcn_mfma_f32_32x32x16_bf16(af[mi], bfv[ni], acc[mi][ni], 0, 0, 0);
    }
  };

  if constexpr (AF32) {
    // ---- counted-vmcnt pipeline ----
    loadA_f32(0);
    writeA_f32();                 // waits its own loads (one-time HBM latency)
    stageB(0);                    // 4 GLDS16 in flight
    __builtin_amdgcn_sched_barrier(0);
    loadA_f32(1);                 // 8 loads in flight, NEWER than stageB
    WAITCNT("vmcnt(8) lgkmcnt(0)");   // drain stageB + ds_writes, keep A loads
    SBAR();

    for (int t = 0; t < NT; ++t) {
      compute_tile();
      WAITCNT("lgkmcnt(0)");
      SBAR();                     // compute-end barrier: vmem stays in flight
      if (t + 1 < NT) {
        stageB(t + 1);            // 4 GLDS16 (oldest of this phase)
        writeA_f32();             // consumes ar (A loads long since landed)
        __builtin_amdgcn_sched_barrier(0);   // pin: stageB before loadA
        if (t + 2 < NT) {
          loadA_f32(t + 2);       // 8 loads, newer than stageB
          WAITCNT("vmcnt(8) lgkmcnt(0)");    // drain stageB only
        } else {
          WAITCNT("vmcnt(0) lgkmcnt(0)");    // tail: full drain
        }
        SBAR();                   // publish t+1
      }
    }
  } else {
    // ---- unchanged r12 structure ----
    stageA_bf(0);
    stageB(0);
    __syncthreads();
    for (int t = 0; t < NT; ++t) {
      compute_tile();
      __syncthreads();
      if (t + 1 < NT) {
        stageB(t + 1);
        stageA_bf(t + 1);
        __syncthreads();
      }
    }
  }

  #pragma unroll
  for (int ni = 0; ni < 2; ++ni) {
    const int col = n0 + wn * 64 + ni * 32 + l31;
    const float bv = bias[col];
    #pragma unroll
    for (int mi = 0; mi < 2; ++mi) {
      #pragma unroll
      for (int g = 0; g < 4; ++g)
        #pragma unroll
        for (int e = 0; e < 4; ++e) {
          const int row = m0 + wm * 64 + mi * 32 + g * 8 + hi * 4 + e;
          const float val = (acc[mi][ni][g * 4 + e] + bv) * scl;
          if constexpr (sizeof(TOUT) == 2)
            C[(size_t)row * DIM + col] = __float2bfloat16(val);
          else
            C[(size_t)row * DIM + col] = val;
        }
    }
  }
}

// ---------------------------------------------------------------------------
// Flash attention (r12-verified): 512 threads = 8 waves, QB=256, 512 blocks.
// Static-max softmax (Q pre-scaled), deferred l reduction, K via GLDS16 with
// pre-swizzled source, V reg-staged transpose-pack.
// ---------------------------------------------------------------------------
__global__ __launch_bounds__(512, 4)
void flash_attn(const __hip_bfloat16* __restrict__ Qb,
                const __hip_bfloat16* __restrict__ Kb,
                const __hip_bfloat16* __restrict__ Vb,
                __hip_bfloat16* __restrict__ Ob)
{
  __shared__ __align__(16) u32 Ks32[2][64][32];
  __shared__ __align__(16) u32 Vt32[2][64][32];

  const int id  = blockIdx.x;
  const int xcd = id & 7;
  const int r_  = id >> 3;
  const int qb  = r_ & 7;
  const int hh  = (r_ >> 3) & 1;
  const int b   = r_ >> 4;
  const int h   = xcd + 8 * hh;

  const int tid = threadIdx.x, lane = tid & 63, w = tid >> 6;
  const int l31 = lane & 31, hi = lane >> 5;

  const size_t headoff = (size_t)h * HDIM;
  const int qrow = b * SEQ + qb * 256 + w * 32 + l31;

  bf16x8 qf[4];
  #pragma unroll
  for (int dk = 0; dk < 4; ++dk)
    qf[dk] = *reinterpret_cast<const bf16x8*>(
      &Qb[(size_t)qrow * DIM + headoff + dk * 16 + hi * 8]);

  f32x16 accO[2] = {};
  float l_run = 0.f;

  const size_t kbase = (size_t)b * SEQ * DIM + headoff;

  const int kr = tid >> 3, kg = tid & 7;
  const __hip_bfloat16* kGptr = Kb + kbase + (size_t)kr * DIM + (kg ^ swz7(kr)) * 8;
  char* const kLbase = (char*)Ks32 + w * 1024;

  const int vkp = tid >> 4;
  const int vdq = tid & 15;
  uint2 vst0, vst1;

  auto loadV = [&](int t) {
    const __hip_bfloat16* vp_ = &Vb[kbase + (size_t)(t * 64 + vkp * 2) * DIM + vdq * 4];
    vst0 = *reinterpret_cast<const uint2*>(vp_);
    vst1 = *reinterpret_cast<const uint2*>(vp_ + DIM);
  };
  auto stageK = [&](int nb, int t) {
    GLDS16(kGptr + (size_t)(t * 64) * DIM, kLbase + nb * 8192);
  };
  auto storeV = [&](int nb) {
    const unsigned short* a  = (const unsigned short*)&vst0;
    const unsigned short* bv = (const unsigned short*)&vst1;
    #pragma unroll
    for (int j = 0; j < 4; ++j) {
      const int row = vdq * 4 + j;
      Vt32[nb][row][vkp ^ swz4(row)] = (u32)a[j] | ((u32)bv[j] << 16);
    }
  };

  stageK(0, 0); loadV(0); storeV(0); __syncthreads();

  for (int t = 0; t < SEQ / 64; ++t) {
    const int bb = t & 1;
    if (t < SEQ / 64 - 1) { stageK(bb ^ 1, t + 1); loadV(t + 1); }

    f32x16 sacc[2] = {};
    __builtin_amdgcn_s_setprio(1);
    #pragma unroll
    for (int kt = 0; kt < 2; ++kt) {
      const int row = kt * 32 + l31;
      const int sk = swz4(row);
      #pragma unroll
      for (int dk = 0; dk < 4; ++dk) {
        bf16x8 kf = *reinterpret_cast<const bf16x8*>(&Ks32[bb][row][(dk * 8 + hi * 4) ^ sk]);
        sacc[kt] = __builtin_amdgcn_mfma_f32_32x32x16_bf16(kf, qf[dk], sacc[kt], 0, 0, 0);
      }
    }
    __builtin_amdgcn_s_setprio(0);

    #pragma unroll
    for (int kt = 0; kt < 2; ++kt)
      #pragma unroll
      for (int r2 = 0; r2 < 16; ++r2)
        sacc[kt][r2] = __builtin_amdgcn_exp2f(sacc[kt][r2]);

    f32x16 ps = sacc[0] + sacc[1];
    float s8[8];
    #pragma unroll
    for (int i = 0; i < 8; ++i) s8[i] = ps[i] + ps[i + 8];
    l_run += ((s8[0] + s8[1]) + (s8[2] + s8[3])) + ((s8[4] + s8[5]) + (s8[6] + s8[7]));

    u32 pf[4][4];
#define MAKE_PF(DST, P, B) do {                                            \
      u32 x1 = cvtpk(P[B+0], P[B+1]);                                      \
      u32 y1 = cvtpk(P[B+4], P[B+5]);                                      \
      u32 x2 = cvtpk(P[B+2], P[B+3]);                                      \
      u32 y2 = cvtpk(P[B+6], P[B+7]);                                      \
      auto s1_ = __builtin_amdgcn_permlane32_swap(x1, y1, false, false);   \
      auto s2_ = __builtin_amdgcn_permlane32_swap(x2, y2, false, false);   \
      DST[0] = (u32)s1_[0]; DST[1] = (u32)s2_[0];                          \
      DST[2] = (u32)s1_[1]; DST[3] = (u32)s2_[1];                          \
    } while (0)
    MAKE_PF(pf[0], sacc[0], 0);
    MAKE_PF(pf[1], sacc[0], 8);
    MAKE_PF(pf[2], sacc[1], 0);
    MAKE_PF(pf[3], sacc[1], 8);
#undef MAKE_PF

    __builtin_amdgcn_s_setprio(1);
    #pragma unroll
    for (int dt = 0; dt < 2; ++dt) {
      const int row = dt * 32 + l31;
      const int sk = swz4(row);
      #pragma unroll
      for (int kf = 0; kf < 4; ++kf) {
        bf16x8 vf = *reinterpret_cast<const bf16x8*>(&Vt32[bb][row][(kf * 8 + hi * 4) ^ sk]);
        union { u32 u[4]; bf16x8 v; } pu;
        pu.u[0] = pf[kf][0]; pu.u[1] = pf[kf][1];
        pu.u[2] = pf[kf][2]; pu.u[3] = pf[kf][3];
        accO[dt] = __builtin_amdgcn_mfma_f32_32x32x16_bf16(vf, pu.v, accO[dt], 0, 0, 0);
      }
    }
    __builtin_amdgcn_s_setprio(0);

    if (t < SEQ / 64 - 1) storeV(bb ^ 1);
    __syncthreads();
  }

  l_run += __shfl_xor(l_run, 32);
  const float inv = 1.f / l_run;
  const size_t rowbase = (size_t)qrow * DIM + headoff;
  #pragma unroll
  for (int dt = 0; dt < 2; ++dt)
    #pragma unroll
    for (int g = 0; g < 4; ++g) {
      ushort4 o;
      o.x = f2bfu(accO[dt][g * 4 + 0] * inv);
      o.y = f2bfu(accO[dt][g * 4 + 1] * inv);
      o.z = f2bfu(accO[dt][g * 4 + 2] * inv);
      o.w = f2bfu(accO[dt][g * 4 + 3] * inv);
      *reinterpret_cast<ushort4*>(&Ob[rowbase + dt * 32 + g * 8 + hi * 4]) = o;
    }
}

// ---------------------------------------------------------------------------
extern "C" void kernel_launch(void* const* d_in, const int* in_sizes, int n_in,
                              void* d_out, int out_size, void* d_ws, size_t ws_size,
                              hipStream_t stream)
{
  const float* q  = (const float*)d_in[0];
  const float* k  = (const float*)d_in[1];
  const float* v  = (const float*)d_in[2];
  const float* wq = (const float*)d_in[3];
  const float* bq = (const float*)d_in[4];
  const float* wk = (const float*)d_in[5];
  const float* bk = (const float*)d_in[6];
  const float* wv = (const float*)d_in[7];
  const float* bv = (const float*)d_in[8];
  const float* wo = (const float*)d_in[9];
  const float* bo = (const float*)d_in[10];

  const size_t MN = (size_t)BATCH * SEQ * DIM;   // 8388608
  const size_t KK = (size_t)DIM * DIM;           // 1048576
  const float  C1 = 0.125f * 1.44269504f;        // softmax scale * log2(e)

  __hip_bfloat16* Qb = (__hip_bfloat16*)d_ws;
  __hip_bfloat16* Kb = Qb + MN;
  __hip_bfloat16* Vb = Kb + MN;
  __hip_bfloat16* S3 = Vb + MN;     // 4th 16MB slot
  __hip_bfloat16* WtQ = S3;         // weights live here until attention
  __hip_bfloat16* WtK = S3 + KK;
  __hip_bfloat16* WtV = S3 + 2 * KK;
  __hip_bfloat16* Ob  = S3;         // attention output overwrites Wt (dead)
  __hip_bfloat16* WtO = (__hip_bfloat16*)d_ws;  // into Qb slot after attention

  wtrans<<<768, 256, 0, stream>>>(wq, wk, wv, WtQ, WtK, WtV);

  gemm1ph<float, __hip_bfloat16, 3><<<1536, 256, 0, stream>>>(
      q, k, v, WtQ, WtK, WtV, bq, bk, bv, Qb, Kb, Vb, C1, 1.0f, 1.0f);

  flash_attn<<<512, 512, 0, stream>>>(Qb, Kb, Vb, Ob);

  wtrans<<<256, 256, 0, stream>>>(wo, wo, wo, WtO, WtO, WtO);

  gemm1ph<__hip_bfloat16, float, 1><<<512, 256, 0, stream>>>(
      Ob, Ob, Ob, WtO, WtO, WtO, bo, bo, bo,
      (float*)d_out, (float*)d_out, (float*)d_out, 1.0f, 1.0f, 1.0f);
}